// Round 6
// baseline (136.012 us; speedup 1.0000x reference)
//
#include <hip/hip_runtime.h>
#include <math.h>

#define EPS 1e-6f
constexpr int B = 8, N = 2048, C = 256, R = 4;

__device__ __forceinline__ float wred_sum(float v) {
  for (int d = 32; d; d >>= 1) v += __shfl_xor(v, d, 64);
  return v;
}

// ww is pointwise given softmax denominator: wg*(ag*alloc + (1-ag)*exp(sw)/denw)
__device__ __forceinline__ float ww_inline(float sw, float al, float dw,
                                           float agv, float wgv) {
  return wgv * (agv * al + (1.f - agv) * (expf(sw) / dw));
}

// ---- K_pre: blocks 0..255 = sort-free alloc; blocks 256..1279 = phiw + denw atomics
__global__ __launch_bounds__(1024) void k_pre(const float* __restrict__ usage,
    const float* __restrict__ wwp, const float* __restrict__ fg,
    const float* __restrict__ rw, const float* __restrict__ mem,
    const float* __restrict__ wk, const float* __restrict__ wstr,
    float* __restrict__ alloc_, float* __restrict__ sw_, float* __restrict__ denw) {
  __shared__ float2 ulg[N];       // 16KB
  __shared__ float Sp[16][64];    // 4KB
  __shared__ float eacc[16];
  int blk = blockIdx.x;
  int t = threadIdx.x;
  if (blk < 256) {
    int b = blk >> 5, chunk = blk & 31;
    float gx = fg[b * R + 0], gy = fg[b * R + 1], gz = fg[b * R + 2], gw2 = fg[b * R + 3];
    for (int e = t; e < N; e += 1024) {
      float4 r4 = *(const float4*)&rw[(size_t)(b * N + e) * R];
      float psi = (1.f - gx * r4.x) * (1.f - gy * r4.y) * (1.f - gz * r4.z) * (1.f - gw2 * r4.w);
      float us = usage[b * N + e], w = wwp[b * N + e];
      float u = (us + w - us * w) * psi;
      ulg[e] = make_float2(u, log2f(u));
    }
    __syncthreads();
    int i = chunk * 64 + (t & 63);
    int jseg = t >> 6;            // 0..15
    float ui = ulg[i].x;
    float S = 0.f;
    int j0 = jseg * 128;
    #pragma unroll 4
    for (int jj = 0; jj < 128; jj++) {
      int j = j0 + jj;
      float2 v = ulg[j];
      bool sel = (v.x < ui) || (v.x == ui && j < i);
      S += sel ? v.y : 0.f;
    }
    Sp[jseg][t & 63] = S;
    __syncthreads();
    if (t < 64) {
      float tot = 0.f;
      #pragma unroll
      for (int s = 0; s < 16; s++) tot += Sp[s][t];
      int ii = chunk * 64 + t;
      alloc_[b * N + ii] = (1.f - ulg[ii].x) * exp2f(tot);
    }
  } else {
    int wv = t >> 6, lane = t & 63;
    int gw = (blk - 256) * 16 + wv;
    int b = gw >> 11, n = gw & (N - 1);
    float4 m4 = *(const float4*)&mem[(size_t)(b * N + n) * C + lane * 4];
    float4 k4 = *(const float4*)&wk[b * C + lane * 4];
    float dot = m4.x * k4.x + m4.y * k4.y + m4.z * k4.z + m4.w * k4.w;
    float nrm = m4.x * m4.x + m4.y * m4.y + m4.z * m4.z + m4.w * m4.w;
    float knr = k4.x * k4.x + k4.y * k4.y + k4.z * k4.z + k4.w * k4.w;
    for (int d = 32; d; d >>= 1) {
      dot += __shfl_xor(dot, d, 64);
      nrm += __shfl_xor(nrm, d, 64);
      knr += __shfl_xor(knr, d, 64);
    }
    if (lane == 0) {
      float phi = dot / (sqrtf(nrm) * sqrtf(knr) + EPS);
      float swv = phi * wstr[b];
      sw_[b * N + n] = swv;
      eacc[wv] = expf(swv);
    }
    __syncthreads();
    if (t == 0) {
      float s = 0.f;
      #pragma unroll
      for (int i = 0; i < 16; i++) s += eacc[i];
      atomicAdd(&denw[b], s);
    }
  }
}

// ---- K_mid: blocks 0..511 linkpass (32-row strips); 512..2559 phir; 2560..2567 ST
__global__ __launch_bounds__(512, 4) void k_mid(const float* __restrict__ link,
    const float* __restrict__ rw, const float* __restrict__ sw_,
    const float* __restrict__ alloc_, const float* __restrict__ denw,
    const float* __restrict__ ag, const float* __restrict__ wg,
    const float* __restrict__ prec, const float* __restrict__ mem,
    const float* __restrict__ rk, const float* __restrict__ ev,
    const float* __restrict__ wvec, const float* __restrict__ rs,
    float* __restrict__ t_, float* __restrict__ upart, float* __restrict__ sr_,
    float* __restrict__ denr, float* __restrict__ ST_) {
  __shared__ float tred[32][8][8];   // 8KB (linkpass)
  __shared__ float ri8[32][8];       // 1KB (linkpass): per-row [rw | ww*rw]
  __shared__ float eacc[8][4];       // (phir)
  __shared__ float red8[8][8];       // (ST)
  const int blk = blockIdx.x;
  const int t = threadIdx.x;
  const int lane = t & 63, wv = t >> 6;
  if (blk < 512) {
    // ======== linkpass: 32-row strip, all 2048 columns ========
    const int b = blk >> 6;
    const int strip = blk & 63;
    const int i0 = strip * 32;
    const int jb = t * 4;
    const float agv = ag[b], wgv = wg[b], dw = denw[b];
    // stage per-row ri into LDS (once per block)
    if (t < 32) {
      int i = i0 + t;
      float4 q = *(const float4*)&rw[(size_t)(b * N + i) * R];
      float wi = ww_inline(sw_[b * N + i], alloc_[b * N + i], dw, agv, wgv);
      ri8[t][0] = q.x; ri8[t][1] = q.y; ri8[t][2] = q.z; ri8[t][3] = q.w;
      ri8[t][4] = wi * q.x; ri8[t][5] = wi * q.y; ri8[t][6] = wi * q.z; ri8[t][7] = wi * q.w;
    }
    float cw[4][8];
    {
      float4 sw4 = *(const float4*)&sw_[b * N + jb];
      float4 al4 = *(const float4*)&alloc_[b * N + jb];
      float wj[4] = { ww_inline(sw4.x, al4.x, dw, agv, wgv),
                      ww_inline(sw4.y, al4.y, dw, agv, wgv),
                      ww_inline(sw4.z, al4.z, dw, agv, wgv),
                      ww_inline(sw4.w, al4.w, dw, agv, wgv) };
      #pragma unroll
      for (int k = 0; k < 4; k++) {
        float4 r4 = *(const float4*)&rw[(size_t)(b * N + jb + k) * R];
        cw[k][0] = r4.x; cw[k][1] = r4.y; cw[k][2] = r4.z; cw[k][3] = r4.w;
        cw[k][4] = wj[k] * r4.x; cw[k][5] = wj[k] * r4.y;
        cw[k][6] = wj[k] * r4.z; cw[k][7] = wj[k] * r4.w;
      }
    }
    float uacc[4][8];
    #pragma unroll
    for (int k = 0; k < 4; k++) {
      #pragma unroll
      for (int r = 0; r < 8; r++) uacc[k][r] = 0.f;
    }
    __syncthreads();
    const float* Lbase = link + (size_t)(b * N + i0) * N;
    for (int ii = 0; ii < 32; ii += 2) {
      float4 La[2];
      La[0] = *(const float4*)(Lbase + (size_t)(ii + 0) * N + jb);
      La[1] = *(const float4*)(Lbase + (size_t)(ii + 1) * N + jb);
      float trow[2][8];
      #pragma unroll
      for (int p = 0; p < 2; p++) {
        float lv[4] = { La[p].x, La[p].y, La[p].z, La[p].w };
        float ri[8];
        #pragma unroll
        for (int r = 0; r < 8; r++) { ri[r] = ri8[ii + p][r]; trow[p][r] = 0.f; }
        #pragma unroll
        for (int k = 0; k < 4; k++) {
          #pragma unroll
          for (int r = 0; r < 8; r++) {
            uacc[k][r] = fmaf(lv[k], ri[r], uacc[k][r]);
            trow[p][r] = fmaf(lv[k], cw[k][r], trow[p][r]);
          }
        }
      }
      // batched butterfly: two independent chains interleave
      float nv[2][4];
      #pragma unroll
      for (int p = 0; p < 2; p++) {
        #pragma unroll
        for (int rr = 0; rr < 4; rr++) {
          float a = trow[p][2 * rr], c = trow[p][2 * rr + 1];
          float oa = __shfl_xor(a, 1, 64), oc = __shfl_xor(c, 1, 64);
          nv[p][rr] = (lane & 1) ? (c + oc) : (a + oa);
        }
      }
      float nw[2][2];
      #pragma unroll
      for (int p = 0; p < 2; p++) {
        #pragma unroll
        for (int rr = 0; rr < 2; rr++) {
          float a = nv[p][2 * rr], c = nv[p][2 * rr + 1];
          float oa = __shfl_xor(a, 2, 64), oc = __shfl_xor(c, 2, 64);
          nw[p][rr] = (lane & 2) ? (c + oc) : (a + oa);
        }
      }
      float vv[2];
      #pragma unroll
      for (int p = 0; p < 2; p++) {
        float a2 = nw[p][0], c2 = nw[p][1];
        float oa2 = __shfl_xor(a2, 4, 64), oc2 = __shfl_xor(c2, 4, 64);
        vv[p] = (lane & 4) ? (c2 + oc2) : (a2 + oa2);
      }
      #pragma unroll
      for (int p = 0; p < 2; p++) vv[p] += __shfl_xor(vv[p], 8, 64);
      #pragma unroll
      for (int p = 0; p < 2; p++) vv[p] += __shfl_xor(vv[p], 16, 64);
      #pragma unroll
      for (int p = 0; p < 2; p++) vv[p] += __shfl_xor(vv[p], 32, 64);
      if (lane < 8) {
        tred[ii + 0][wv][lane] = vv[0];
        tred[ii + 1][wv][lane] = vv[1];
      }
    }
    __syncthreads();
    if (t < 256) {
      int i = t >> 3, r = t & 7;
      float s = 0.f;
      #pragma unroll
      for (int w8 = 0; w8 < 8; w8++) s += tred[i][w8][r];
      t_[((size_t)(b * 8 + r)) * N + i0 + i] = s;   // [b][r8][n]
    }
    // upart [b][strip64][r8][n]
    float* ub = upart + ((size_t)(b * 64 + strip) * 8) * N;
    #pragma unroll
    for (int r = 0; r < 8; r++) {
      float4 v = { uacc[0][r], uacc[1][r], uacc[2][r], uacc[3][r] };
      *(float4*)(ub + (size_t)r * N + jb) = v;
    }
  } else if (blk < 2560) {
    // ======== phir: 8 rows per block + denr atomics ========
    int gw = (blk - 512) * 8 + wv;
    int b = gw >> 11, n = gw & (N - 1);
    const float agv = ag[b], wgv = wg[b], dw = denw[b];
    float w = ww_inline(sw_[b * N + n], alloc_[b * N + n], dw, agv, wgv);
    int c0 = lane * 4;
    float4 m4 = *(const float4*)&mem[(size_t)(b * N + n) * C + c0];
    float4 e4 = *(const float4*)&ev[b * C + c0];
    float4 v4 = *(const float4*)&wvec[b * C + c0];
    float mn[4] = { m4.x * (1.f - w * e4.x) + w * v4.x,
                    m4.y * (1.f - w * e4.y) + w * v4.y,
                    m4.z * (1.f - w * e4.z) + w * v4.z,
                    m4.w * (1.f - w * e4.w) + w * v4.w };
    float dot[4] = { 0, 0, 0, 0 };
    float kn[4] = { 0, 0, 0, 0 };
    float nrm = 0.f;
    #pragma unroll
    for (int ci = 0; ci < 4; ci++) {
      float4 k4 = *(const float4*)&rk[(size_t)(b * C + c0 + ci) * R];
      dot[0] = fmaf(mn[ci], k4.x, dot[0]);
      dot[1] = fmaf(mn[ci], k4.y, dot[1]);
      dot[2] = fmaf(mn[ci], k4.z, dot[2]);
      dot[3] = fmaf(mn[ci], k4.w, dot[3]);
      kn[0] = fmaf(k4.x, k4.x, kn[0]);
      kn[1] = fmaf(k4.y, k4.y, kn[1]);
      kn[2] = fmaf(k4.z, k4.z, kn[2]);
      kn[3] = fmaf(k4.w, k4.w, kn[3]);
      nrm = fmaf(mn[ci], mn[ci], nrm);
    }
    for (int d = 32; d; d >>= 1) {
      dot[0] += __shfl_xor(dot[0], d, 64);
      dot[1] += __shfl_xor(dot[1], d, 64);
      dot[2] += __shfl_xor(dot[2], d, 64);
      dot[3] += __shfl_xor(dot[3], d, 64);
      kn[0] += __shfl_xor(kn[0], d, 64);
      kn[1] += __shfl_xor(kn[1], d, 64);
      kn[2] += __shfl_xor(kn[2], d, 64);
      kn[3] += __shfl_xor(kn[3], d, 64);
      nrm += __shfl_xor(nrm, d, 64);
    }
    if (lane == 0) {
      float mnorm = sqrtf(nrm);
      #pragma unroll
      for (int r = 0; r < 4; r++) {
        float phi = dot[r] / (mnorm * sqrtf(kn[r]) + EPS);
        float sv = phi * rs[b * R + r];
        sr_[(size_t)(b * R + r) * N + n] = sv;
        eacc[wv][r] = expf(sv);
      }
    }
    __syncthreads();
    if (t < 4) {
      float s = 0.f;
      #pragma unroll
      for (int i = 0; i < 8; i++) s += eacc[i][t];
      atomicAdd(&denr[b * R + t], s);
    }
  } else {
    // ======== ST: one block per batch ========
    int b = blk - 2560;
    const float agv = ag[b], wgv = wg[b], dw = denw[b];
    float a[8] = { 0, 0, 0, 0, 0, 0, 0, 0 };
    #pragma unroll
    for (int k = 0; k < 4; k++) {
      int i = t + k * 512;
      float4 r4 = *(const float4*)&rw[(size_t)(b * N + i) * R];
      float pc = prec[b * N + i];
      float w = ww_inline(sw_[b * N + i], alloc_[b * N + i], dw, agv, wgv);
      a[0] = fmaf(pc, r4.x, a[0]); a[1] = fmaf(pc, r4.y, a[1]);
      a[2] = fmaf(pc, r4.z, a[2]); a[3] = fmaf(pc, r4.w, a[3]);
      a[4] = fmaf(w, r4.x, a[4]);  a[5] = fmaf(w, r4.y, a[5]);
      a[6] = fmaf(w, r4.z, a[6]);  a[7] = fmaf(w, r4.w, a[7]);
    }
    #pragma unroll
    for (int r = 0; r < 8; r++) a[r] = wred_sum(a[r]);
    if (lane == 0) {
      #pragma unroll
      for (int r = 0; r < 8; r++) red8[wv][r] = a[r];
    }
    __syncthreads();
    if (t < 8) {
      float s = 0.f;
      #pragma unroll
      for (int i = 0; i < 8; i++) s += red8[i][t];
      ST_[b * 8 + t] = s;
    }
  }
}

// ---- K_combread: strip-reduce u, rwn in LDS, then read_vectors partials
__global__ __launch_bounds__(256) void k_combread(const float* __restrict__ link,
    const float* __restrict__ sw_, const float* __restrict__ alloc_,
    const float* __restrict__ denw, const float* __restrict__ denr,
    const float* __restrict__ ag, const float* __restrict__ wg,
    const float* __restrict__ prec, const float* __restrict__ rw,
    const float* __restrict__ t_, const float* __restrict__ upart,
    const float* __restrict__ sr_, const float* __restrict__ ST_,
    const float* __restrict__ modes, const float* __restrict__ mem,
    const float* __restrict__ ev, const float* __restrict__ wvec,
    float* __restrict__ part_) {
  __shared__ float dgl[64], wloc[64], rwnl[4][64];
  __shared__ float red[4][64][4][4];   // 16KB
  const int blk = blockIdx.x;
  const int b = blk >> 5, chunk = blk & 31;
  const int n0 = chunk * 64;
  const int t = threadIdx.x;
  const int nl = t & 63, r = t >> 6;
  const int n = n0 + nl;
  const float agv = ag[b], wgv = wg[b], dw = denw[b];
  float u1 = 0.f, u2 = 0.f;
  const float* up = upart + ((size_t)(b * 64) * 8) * N;
  #pragma unroll 8
  for (int s = 0; s < 64; s++) {
    const float* p = up + ((size_t)s * 8) * N;
    u1 += p[(size_t)r * N + n];
    u2 += p[(size_t)(4 + r) * N + n];
  }
  float pc = prec[b * N + n];
  if (r == 0) {
    float w = ww_inline(sw_[b * N + n], alloc_[b * N + n], dw, agv, wgv);
    float L = link[((size_t)(b * N + n)) * N + n];
    dgl[nl] = (1.f - 2.f * w) * L + w * pc;
    wloc[nl] = w;
  }
  __syncthreads();
  {
    float w = wloc[nl], Dg = dgl[nl];
    float t1 = t_[(size_t)(b * 8 + r) * N + n];
    float t2 = t_[(size_t)(b * 8 + 4 + r) * N + n];
    float sv = sr_[(size_t)(b * R + r) * N + n];
    float cr = expf(sv) / denr[b * R + r];
    float rv = rw[(size_t)(b * N + n) * R + r];
    float S = ST_[b * 8 + r], T = ST_[b * 8 + 4 + r];
    float m0 = modes[(b * 3 + 0) * R + r], m1 = modes[(b * 3 + 1) * R + r],
          m2 = modes[(b * 3 + 2) * R + r];
    float fwd = (1.f - w) * t1 - t2 + w * S - Dg * rv;
    float bwd = (1.f - w) * u1 - u2 + pc * T - Dg * rv;
    rwnl[r][nl] = m0 * bwd + m1 * cr + m2 * fwd;
  }
  __syncthreads();
  const int sub = r, cg = nl;
  const int c0 = cg * 4;
  float4 e4 = *(const float4*)&ev[b * C + c0];
  float4 v4 = *(const float4*)&wvec[b * C + c0];
  float acc[4][4];
  #pragma unroll
  for (int ci = 0; ci < 4; ci++) {
    #pragma unroll
    for (int rr = 0; rr < 4; rr++) acc[ci][rr] = 0.f;
  }
  for (int m = 0; m < 16; m++) {
    int row = sub * 16 + m;
    int nn = n0 + row;
    float w = wloc[row];
    float4 m4 = *(const float4*)&mem[(size_t)(b * N + nn) * C + c0];
    float mn[4] = { m4.x * (1.f - w * e4.x) + w * v4.x,
                    m4.y * (1.f - w * e4.y) + w * v4.y,
                    m4.z * (1.f - w * e4.z) + w * v4.z,
                    m4.w * (1.f - w * e4.w) + w * v4.w };
    float rv[4] = { rwnl[0][row], rwnl[1][row], rwnl[2][row], rwnl[3][row] };
    #pragma unroll
    for (int ci = 0; ci < 4; ci++) {
      #pragma unroll
      for (int rr = 0; rr < 4; rr++) acc[ci][rr] = fmaf(mn[ci], rv[rr], acc[ci][rr]);
    }
  }
  #pragma unroll
  for (int ci = 0; ci < 4; ci++) {
    #pragma unroll
    for (int rr = 0; rr < 4; rr++) red[sub][cg][ci][rr] = acc[ci][rr];
  }
  __syncthreads();
  if (sub == 0) {
    #pragma unroll
    for (int ci = 0; ci < 4; ci++) {
      #pragma unroll
      for (int rr = 0; rr < 4; rr++) {
        float s = red[0][cg][ci][rr] + red[1][cg][ci][rr] +
                  red[2][cg][ci][rr] + red[3][cg][ci][rr];
        part_[((size_t)blk * C + (c0 + ci)) * R + rr] = s;
      }
    }
  }
}

// ---- K_final: reduce 32 chunk partials -> out [B][C][R]
__global__ void k_final(const float* __restrict__ part_, float* __restrict__ out) {
  int idx = blockIdx.x * 256 + threadIdx.x;
  if (idx >= B * C * R) return;
  int b = idx / (C * R), cr = idx % (C * R);
  float s = 0.f;
  for (int ch = 0; ch < 32; ch++) s += part_[(size_t)(b * 32 + ch) * C * R + cr];
  out[idx] = s;
}

extern "C" void kernel_launch(void* const* d_in, const int* in_sizes, int n_in,
                              void* d_out, int out_size, void* d_ws, size_t ws_size,
                              hipStream_t stream) {
  const float* mem   = (const float*)d_in[0];
  const float* link  = (const float*)d_in[1];
  const float* usage = (const float*)d_in[2];
  const float* rw    = (const float*)d_in[3];
  const float* wwp   = (const float*)d_in[4];
  const float* prec  = (const float*)d_in[5];
  const float* rk    = (const float*)d_in[6];
  const float* rs    = (const float*)d_in[7];
  const float* wk    = (const float*)d_in[8];
  const float* wstr  = (const float*)d_in[9];
  const float* fg    = (const float*)d_in[10];
  const float* ag    = (const float*)d_in[11];
  const float* wg    = (const float*)d_in[12];
  const float* wvec  = (const float*)d_in[13];
  const float* ev    = (const float*)d_in[14];
  const float* modes = (const float*)d_in[15];
  float* out = (float*)d_out;

  float* W = (float*)d_ws;
  float* denw  = W;                   // 8
  float* denr  = W + 8;               // 32 (pad to 64)
  float* alloc_= W + 64;              // B*N
  float* sw_   = alloc_ + B * N;      // B*N
  float* ST_   = sw_ + B * N;         // 64
  float* t_    = ST_ + 64;            // B*8*N
  float* sr_   = t_ + B * 8 * N;      // B*R*N
  float* part_ = sr_ + B * R * N;     // B*32*C*R
  float* upart = part_ + B * 32 * C * R;  // B*64*8*N = 32MB

  (void)hipMemsetAsync(W, 0, 64 * sizeof(float), stream);
  k_pre<<<256 + (B * N) / 16, 1024, 0, stream>>>(usage, wwp, fg, rw, mem, wk, wstr,
                                                 alloc_, sw_, denw);
  k_mid<<<512 + (B * N) / 8 + B, 512, 0, stream>>>(link, rw, sw_, alloc_, denw, ag, wg,
                                                   prec, mem, rk, ev, wvec, rs,
                                                   t_, upart, sr_, denr, ST_);
  k_combread<<<B * 32, 256, 0, stream>>>(link, sw_, alloc_, denw, denr, ag, wg, prec,
                                         rw, t_, upart, sr_, ST_, modes, mem, ev,
                                         wvec, part_);
  k_final<<<(B * C * R) / 256, 256, 0, stream>>>(part_, out);
}